// Round 7
// baseline (4608.073 us; speedup 1.0000x reference)
//
#include <hip/hip_runtime.h>
#include <hip/hip_bf16.h>

// ---------------------------------------------------------------------------
// Fully fake-quantized Llama MLP on MI355X (gfx950).
// Device inputs: float32. Device output: float32.
// Intermediates bf16; GEMMs via bf16 MFMA 16x16x32, f32 accumulate.
// R7: 5 blocks/CU GEMM; unique kernel names for profile visibility.
// ---------------------------------------------------------------------------

typedef __bf16 bf16x8 __attribute__((ext_vector_type(8)));
typedef float f32x4 __attribute__((ext_vector_type(4)));
typedef unsigned short ushort8 __attribute__((ext_vector_type(8)));
typedef unsigned short u16;

#define SLOT_X 0
#define SLOT_UP 1
#define SLOT_GATE 2
#define SLOT_G2 3
#define SLOT_O 4

__device__ __forceinline__ float bf2f(u16 u) {
    return __uint_as_float(((unsigned)u) << 16);
}
__device__ __forceinline__ u16 f2bf(float f) {
    unsigned x = __float_as_uint(f);
    unsigned r = (x + 0x7FFFu + ((x >> 16) & 1u)) >> 16;  // RNE
    return (u16)r;
}

__device__ __forceinline__ unsigned encf(float f) {
    unsigned u = __float_as_uint(f);
    return (u & 0x80000000u) ? ~u : (u | 0x80000000u);
}
__device__ __forceinline__ float decf(unsigned s) {
    unsigned u = (s & 0x80000000u) ? (s ^ 0x80000000u) : ~s;
    return __uint_as_float(u);
}

__device__ __forceinline__ void wave_minmax_atomic(float mn, float mx, unsigned* slots, int sidx) {
    for (int off = 32; off; off >>= 1) {
        mn = fminf(mn, __shfl_xor(mn, off));
        mx = fmaxf(mx, __shfl_xor(mx, off));
    }
    if ((threadIdx.x & 63) == 0) {
        atomicMin(&slots[sidx * 2 + 0], encf(mn));
        atomicMax(&slots[sidx * 2 + 1], encf(mx));
    }
}

__device__ __forceinline__ void get_scale_zp(const unsigned* slots, int sidx, float& scale, float& zp) {
    float mn = decf(slots[sidx * 2 + 0]);
    float mx = decf(slots[sidx * 2 + 1]);
    scale = fmaxf((mx - mn) / 65535.0f, 1e-12f);
    zp = fminf(fmaxf(rintf(-mn / scale), 0.0f), 65535.0f);
}

__device__ __forceinline__ float qdq_act(float x, float scale, float zp) {
    float q = rintf(x / scale) + zp;
    q = fminf(fmaxf(q, 0.0f), 65535.0f);
    return (q - zp) * scale;
}

__device__ __forceinline__ void load_lds16(const void* g, void* l) {
    __builtin_amdgcn_global_load_lds((const __attribute__((address_space(1))) void*)g,
                                     (__attribute__((address_space(3))) void*)l, 16, 0, 0);
}

// ---------------------------------------------------------------------------
__global__ void init_slots(unsigned* slots) {
    if (threadIdx.x < 16) slots[threadIdx.x] = 0x80000000u;  // enc(0.0f)
}

__global__ __launch_bounds__(256) void minmax_x(const float* __restrict__ in, long n,
                                                unsigned* slots, int sidx) {
    long stride = (long)gridDim.x * blockDim.x * 4;
    float mn = 0.f, mx = 0.f;
    for (long i = ((long)blockIdx.x * blockDim.x + threadIdx.x) * 4; i < n; i += stride) {
        float4 v = *(const float4*)(in + i);
        mn = fminf(fminf(mn, fminf(v.x, v.y)), fminf(v.z, v.w));
        mx = fmaxf(fmaxf(mx, fmaxf(v.x, v.y)), fmaxf(v.z, v.w));
    }
    wave_minmax_atomic(mn, mx, slots, sidx);
}

__global__ __launch_bounds__(256) void qdq_x_kernel(const float* __restrict__ in, u16* __restrict__ out,
                                                    long n, const unsigned* slots, int sidx) {
    float scale, zp;
    get_scale_zp(slots, sidx, scale, zp);
    long stride = (long)gridDim.x * blockDim.x * 8;
    for (long i = ((long)blockIdx.x * blockDim.x + threadIdx.x) * 8; i < n; i += stride) {
        float4 a = *(const float4*)(in + i);
        float4 b = *(const float4*)(in + i + 4);
        ushort8 o;
        o[0] = f2bf(qdq_act(a.x, scale, zp));
        o[1] = f2bf(qdq_act(a.y, scale, zp));
        o[2] = f2bf(qdq_act(a.z, scale, zp));
        o[3] = f2bf(qdq_act(a.w, scale, zp));
        o[4] = f2bf(qdq_act(b.x, scale, zp));
        o[5] = f2bf(qdq_act(b.y, scale, zp));
        o[6] = f2bf(qdq_act(b.z, scale, zp));
        o[7] = f2bf(qdq_act(b.w, scale, zp));
        *(ushort8*)(out + i) = o;
    }
}

// per-(row, 32-block) symmetric 4-bit weight fake-quant; f32 -> bf16.
// 4 lanes per 32-elem block; coalesced (wave reads 2 KB contiguous).
__device__ __forceinline__ void quant_w_body(const float* __restrict__ W, u16* __restrict__ Wq, long nblk) {
    long ngrp = (long)gridDim.x * blockDim.x / 4;
    long g0 = ((long)blockIdx.x * blockDim.x + threadIdx.x) / 4;
    int j = threadIdx.x & 3;
    for (long b = g0; b < nblk; b += ngrp) {
        const float* p = W + b * 32 + j * 8;
        float4 u0 = *(const float4*)(p);
        float4 u1 = *(const float4*)(p + 4);
        float am = fmaxf(fmaxf(fmaxf(fabsf(u0.x), fabsf(u0.y)), fmaxf(fabsf(u0.z), fabsf(u0.w))),
                         fmaxf(fmaxf(fabsf(u1.x), fabsf(u1.y)), fmaxf(fabsf(u1.z), fabsf(u1.w))));
        am = fmaxf(am, __shfl_xor(am, 1));
        am = fmaxf(am, __shfl_xor(am, 2));
        float scale = fmaxf(am / 7.0f, 1e-12f);
        float inv = 1.0f / scale;
        float v[8] = {u0.x, u0.y, u0.z, u0.w, u1.x, u1.y, u1.z, u1.w};
        ushort8 o;
        #pragma unroll
        for (int t = 0; t < 8; ++t) {
            float q = rintf(v[t] * inv);
            q = fminf(fmaxf(q, -8.0f), 7.0f);
            o[t] = f2bf(q * scale);
        }
        *(ushort8*)(Wq + b * 32 + j * 8) = o;
    }
}
__global__ __launch_bounds__(256) void quant_w_up(const float* W, u16* Wq, long nblk)   { quant_w_body(W, Wq, nblk); }
__global__ __launch_bounds__(256) void quant_w_gate(const float* W, u16* Wq, long nblk) { quant_w_body(W, Wq, nblk); }
__global__ __launch_bounds__(256) void quant_w_down(const float* W, u16* Wq, long nblk) { quant_w_body(W, Wq, nblk); }

// elementwise chain: g1=qdq(gate); sig=fixed_qdq(sigmoid(g1)); g2=g1*sig;
// STAGE1: minmax(g2) -> SLOT_G2
// STAGE2: o = qdq(g2)*qdq(up); minmax(o) -> SLOT_O
// STAGE3: out = bf16(qdq(o))   (out aliases gate; same-index RAW per thread)
template <int STAGEI>
__device__ __forceinline__ void epass_body(const u16* gate, const u16* up, u16* out,
                                           long n, unsigned* slots) {
    float g_s, g_z, u_s = 1.f, u_z = 0.f, g2_s = 1.f, g2_z = 0.f, o_s = 1.f, o_z = 0.f;
    get_scale_zp(slots, SLOT_GATE, g_s, g_z);
    if (STAGEI >= 2) {
        get_scale_zp(slots, SLOT_UP, u_s, u_z);
        get_scale_zp(slots, SLOT_G2, g2_s, g2_z);
    }
    if (STAGEI >= 3) get_scale_zp(slots, SLOT_O, o_s, o_z);

    long stride = (long)gridDim.x * blockDim.x * 8;
    float mn = 0.f, mx = 0.f;
    for (long i = ((long)blockIdx.x * blockDim.x + threadIdx.x) * 8; i < n; i += stride) {
        ushort8 gv = *(const ushort8*)(gate + i);
        ushort8 uv;
        if (STAGEI >= 2) uv = *(const ushort8*)(up + i);
        ushort8 ov;
        #pragma unroll
        for (int j = 0; j < 8; ++j) {
            float g1 = qdq_act(bf2f(gv[j]), g_s, g_z);
            float s = 1.0f / (1.0f + __expf(-g1));
            float sq = fminf(fmaxf(rintf(s * 65536.0f), 0.0f), 65535.0f) * (1.0f / 65536.0f);
            float g2 = g1 * sq;
            if (STAGEI == 1) {
                mn = fminf(mn, g2);
                mx = fmaxf(mx, g2);
            } else {
                float g2q = qdq_act(g2, g2_s, g2_z);
                float u1 = qdq_act(bf2f(uv[j]), u_s, u_z);
                float o = g2q * u1;
                if (STAGEI == 2) {
                    mn = fminf(mn, o);
                    mx = fmaxf(mx, o);
                } else {
                    ov[j] = f2bf(qdq_act(o, o_s, o_z));
                }
            }
        }
        if (STAGEI == 3) *(ushort8*)(out + i) = ov;
    }
    if (STAGEI == 1) wave_minmax_atomic(mn, mx, slots, SLOT_G2);
    if (STAGEI == 2) wave_minmax_atomic(mn, mx, slots, SLOT_O);
}
__global__ __launch_bounds__(256) void epass1(const u16* g, const u16* u, u16* o, long n, unsigned* s) { epass_body<1>(g, u, o, n, s); }
__global__ __launch_bounds__(256) void epass2(const u16* g, const u16* u, u16* o, long n, unsigned* s) { epass_body<2>(g, u, o, n, s); }
__global__ __launch_bounds__(256) void epass3(const u16* g, const u16* u, u16* o, long n, unsigned* s) { epass_body<3>(g, u, o, n, s); }

// ---------------------------------------------------------------------------
// C = A @ B^T : A [M,K] bf16 row-major, B [N,K] bf16 row-major.
// C is bf16 (u16) or f32 per OutT. 128x128 tile, BK=64, 4 waves (2x2),
// each wave 64x64 via 4x4 mfma_16x16x32. Optionally fuses global min/max.
// Grid: 1D supertiled (SUPER_M=16, bm-inner): concurrent blocks cover a
// 16-row x ~40-col tile rectangle -> working set L3-resident.
// 5 blocks/CU (LDS 5x32KB = 160KB exactly; VGPR 60 <= 102).
template <bool MINMAX, typename OutT>
__device__ __forceinline__ void gemm_body(const u16* __restrict__ A, const u16* __restrict__ B,
                                          OutT* __restrict__ C, int M, int N, int K,
                                          unsigned* slots, int sidx) {
    __shared__ u16 Als[128 * 64];
    __shared__ u16 Bls[128 * 64];
    const int wave = threadIdx.x >> 6;
    const int lane = threadIdx.x & 63;
    const int wr = wave >> 1, wc = wave & 1;
    const int l15 = lane & 15, lhi = lane >> 4;

    // supertile mapping: stripes of 16 bm; within a stripe bm varies fastest
    const int ntn = N >> 7;
    const int rowspan = 16 * ntn;
    const int stripe = blockIdx.x / rowspan;
    const int rem = blockIdx.x - stripe * rowspan;
    const int bn = rem >> 4;
    const int bm = (stripe << 4) + (rem & 15);

    f32x4 acc[4][4] = {};

    const u16* Abase = A + (size_t)bm * 128 * K;
    const u16* Bbase = B + (size_t)bn * 128 * K;

    for (int k0 = 0; k0 < K; k0 += 64) {
        #pragma unroll
        for (int i = 0; i < 4; ++i) {
            int c = i * 4 + wave;            // 16 chunks of 512 elems (1KB/wave-inst)
            int e = c * 512 + lane * 8;
            int row = e >> 6, col = e & 63;
            load_lds16(Abase + (size_t)row * K + k0 + col, &Als[c * 512]);
        }
        #pragma unroll
        for (int i = 0; i < 4; ++i) {
            int c = i * 4 + wave;
            int e = c * 512 + lane * 8;
            int row = e >> 6, col = e & 63;
            load_lds16(Bbase + (size_t)row * K + k0 + col, &Bls[c * 512]);
        }
        __syncthreads();
        #pragma unroll
        for (int kk = 0; kk < 64; kk += 32) {
            bf16x8 af[4], bfr[4];
            #pragma unroll
            for (int m = 0; m < 4; ++m)
                af[m] = *(const bf16x8*)&Als[(wr * 64 + m * 16 + l15) * 64 + kk + lhi * 8];
            #pragma unroll
            for (int n = 0; n < 4; ++n)
                bfr[n] = *(const bf16x8*)&Bls[(wc * 64 + n * 16 + l15) * 64 + kk + lhi * 8];
            #pragma unroll
            for (int m = 0; m < 4; ++m)
                #pragma unroll
                for (int n = 0; n < 4; ++n)
                    acc[m][n] = __builtin_amdgcn_mfma_f32_16x16x32_bf16(af[m], bfr[n], acc[m][n], 0, 0, 0);
        }
        __syncthreads();
    }

    float mn = 0.f, mx = 0.f;
    #pragma unroll
    for (int m = 0; m < 4; ++m) {
        #pragma unroll
        for (int n = 0; n < 4; ++n) {
            int col = bn * 128 + wc * 64 + n * 16 + l15;
            int row0 = bm * 128 + wr * 64 + m * 16 + lhi * 4;
            #pragma unroll
            for (int j = 0; j < 4; ++j) {
                float f = acc[m][n][j];
                if (sizeof(OutT) == 2) {
                    u16 h = f2bf(f);
                    ((u16*)C)[(size_t)(row0 + j) * N + col] = h;
                    if (MINMAX) {
                        float g = bf2f(h);
                        mn = fminf(mn, g);
                        mx = fmaxf(mx, g);
                    }
                } else {
                    ((float*)C)[(size_t)(row0 + j) * N + col] = f;
                    if (MINMAX) {
                        mn = fminf(mn, f);
                        mx = fmaxf(mx, f);
                    }
                }
            }
        }
    }
    if (MINMAX) wave_minmax_atomic(mn, mx, slots, sidx);
}

__global__ __launch_bounds__(256, 5) void gemm_up(const u16* A, const u16* B, u16* C,
                                                  int M, int N, int K, unsigned* slots, int sidx) {
    gemm_body<true, u16>(A, B, C, M, N, K, slots, sidx);
}
__global__ __launch_bounds__(256, 5) void gemm_gate(const u16* A, const u16* B, u16* C,
                                                    int M, int N, int K, unsigned* slots, int sidx) {
    gemm_body<true, u16>(A, B, C, M, N, K, slots, sidx);
}
__global__ __launch_bounds__(256, 5) void gemm_down(const u16* A, const u16* B, float* C,
                                                    int M, int N, int K, unsigned* slots, int sidx) {
    gemm_body<false, float>(A, B, C, M, N, K, slots, sidx);
}

// ---------------------------------------------------------------------------
extern "C" void kernel_launch(void* const* d_in, const int* in_sizes, int n_in,
                              void* d_out, int out_size, void* d_ws, size_t ws_size,
                              hipStream_t stream) {
    const float* x  = (const float*)d_in[0];   // [2,2048,4096] f32
    const float* wg = (const float*)d_in[1];   // [11008,4096] f32
    const float* wu = (const float*)d_in[2];   // [11008,4096] f32
    const float* wd = (const float*)d_in[3];   // [4096,11008] f32
    float* out = (float*)d_out;                // [2,2048,4096] f32

    const int M = 4096, H = 4096, I = 11008;
    const long NX = (long)M * H;
    const long NW = (long)I * H;

    char* ws = (char*)d_ws;
    unsigned* slots = (unsigned*)ws;
    u16* xq    = (u16*)(ws + 256);
    u16* wqs   = (u16*)(ws + 256 + 33554432UL);
    u16* upb   = (u16*)(ws + 256 + 33554432UL + 90177536UL);
    u16* gateb = (u16*)(ws + 256 + 33554432UL + 2 * 90177536UL);

    init_slots<<<1, 64, 0, stream>>>(slots);
    minmax_x<<<4096, 256, 0, stream>>>(x, NX, slots, SLOT_X);
    qdq_x_kernel<<<4096, 256, 0, stream>>>(x, xq, NX, slots, SLOT_X);

    const int nwg_ug = (M / 128) * (I / 128);   // 32*86 = 2752
    const int nwg_d  = (M / 128) * (H / 128);   // 32*32 = 1024

    quant_w_up<<<4096, 256, 0, stream>>>(wu, wqs, NW / 32);
    gemm_up<<<nwg_ug, 256, 0, stream>>>(xq, wqs, upb, M, I, H, slots, SLOT_UP);

    quant_w_gate<<<4096, 256, 0, stream>>>(wg, wqs, NW / 32);
    gemm_gate<<<nwg_ug, 256, 0, stream>>>(xq, wqs, gateb, M, I, H, slots, SLOT_GATE);

    epass1<<<4096, 256, 0, stream>>>(gateb, nullptr, nullptr, NW, slots);
    epass2<<<4096, 256, 0, stream>>>(gateb, upb, nullptr, NW, slots);
    epass3<<<4096, 256, 0, stream>>>(gateb, upb, gateb, NW, slots);

    quant_w_down<<<4096, 256, 0, stream>>>(wd, wqs, NW / 32);
    gemm_down<<<nwg_d, 256, 0, stream>>>(gateb, wqs, out, M, H, I, nullptr, 0);
}

// Round 8
// 2605.584 us; speedup vs baseline: 1.7685x; 1.7685x over previous
//
#include <hip/hip_runtime.h>
#include <hip/hip_bf16.h>

// ---------------------------------------------------------------------------
// Fully fake-quantized Llama MLP on MI355X (gfx950).
// Device inputs: float32. Device output: float32.
// Intermediates bf16; GEMMs via bf16 MFMA 16x16x32, f32 accumulate.
// R8: revert GEMM to proven (256,4) config — (256,5) forced acc spill
//     (VGPR budget 102 < 60 VGPR + 64 AGPR needed; 2.7 GB scratch writes).
//     Unique kernel names kept for tail profiling.
// ---------------------------------------------------------------------------

typedef __bf16 bf16x8 __attribute__((ext_vector_type(8)));
typedef float f32x4 __attribute__((ext_vector_type(4)));
typedef unsigned short ushort8 __attribute__((ext_vector_type(8)));
typedef unsigned short u16;

#define SLOT_X 0
#define SLOT_UP 1
#define SLOT_GATE 2
#define SLOT_G2 3
#define SLOT_O 4

__device__ __forceinline__ float bf2f(u16 u) {
    return __uint_as_float(((unsigned)u) << 16);
}
__device__ __forceinline__ u16 f2bf(float f) {
    unsigned x = __float_as_uint(f);
    unsigned r = (x + 0x7FFFu + ((x >> 16) & 1u)) >> 16;  // RNE
    return (u16)r;
}

__device__ __forceinline__ unsigned encf(float f) {
    unsigned u = __float_as_uint(f);
    return (u & 0x80000000u) ? ~u : (u | 0x80000000u);
}
__device__ __forceinline__ float decf(unsigned s) {
    unsigned u = (s & 0x80000000u) ? (s ^ 0x80000000u) : ~s;
    return __uint_as_float(u);
}

__device__ __forceinline__ void wave_minmax_atomic(float mn, float mx, unsigned* slots, int sidx) {
    for (int off = 32; off; off >>= 1) {
        mn = fminf(mn, __shfl_xor(mn, off));
        mx = fmaxf(mx, __shfl_xor(mx, off));
    }
    if ((threadIdx.x & 63) == 0) {
        atomicMin(&slots[sidx * 2 + 0], encf(mn));
        atomicMax(&slots[sidx * 2 + 1], encf(mx));
    }
}

__device__ __forceinline__ void get_scale_zp(const unsigned* slots, int sidx, float& scale, float& zp) {
    float mn = decf(slots[sidx * 2 + 0]);
    float mx = decf(slots[sidx * 2 + 1]);
    scale = fmaxf((mx - mn) / 65535.0f, 1e-12f);
    zp = fminf(fmaxf(rintf(-mn / scale), 0.0f), 65535.0f);
}

__device__ __forceinline__ float qdq_act(float x, float scale, float zp) {
    float q = rintf(x / scale) + zp;
    q = fminf(fmaxf(q, 0.0f), 65535.0f);
    return (q - zp) * scale;
}

__device__ __forceinline__ void load_lds16(const void* g, void* l) {
    __builtin_amdgcn_global_load_lds((const __attribute__((address_space(1))) void*)g,
                                     (__attribute__((address_space(3))) void*)l, 16, 0, 0);
}

// ---------------------------------------------------------------------------
__global__ void init_slots(unsigned* slots) {
    if (threadIdx.x < 16) slots[threadIdx.x] = 0x80000000u;  // enc(0.0f)
}

__global__ __launch_bounds__(256) void minmax_x(const float* __restrict__ in, long n,
                                                unsigned* slots, int sidx) {
    long stride = (long)gridDim.x * blockDim.x * 4;
    float mn = 0.f, mx = 0.f;
    for (long i = ((long)blockIdx.x * blockDim.x + threadIdx.x) * 4; i < n; i += stride) {
        float4 v = *(const float4*)(in + i);
        mn = fminf(fminf(mn, fminf(v.x, v.y)), fminf(v.z, v.w));
        mx = fmaxf(fmaxf(mx, fmaxf(v.x, v.y)), fmaxf(v.z, v.w));
    }
    wave_minmax_atomic(mn, mx, slots, sidx);
}

__global__ __launch_bounds__(256) void qdq_x_kernel(const float* __restrict__ in, u16* __restrict__ out,
                                                    long n, const unsigned* slots, int sidx) {
    float scale, zp;
    get_scale_zp(slots, sidx, scale, zp);
    long stride = (long)gridDim.x * blockDim.x * 8;
    for (long i = ((long)blockIdx.x * blockDim.x + threadIdx.x) * 8; i < n; i += stride) {
        float4 a = *(const float4*)(in + i);
        float4 b = *(const float4*)(in + i + 4);
        ushort8 o;
        o[0] = f2bf(qdq_act(a.x, scale, zp));
        o[1] = f2bf(qdq_act(a.y, scale, zp));
        o[2] = f2bf(qdq_act(a.z, scale, zp));
        o[3] = f2bf(qdq_act(a.w, scale, zp));
        o[4] = f2bf(qdq_act(b.x, scale, zp));
        o[5] = f2bf(qdq_act(b.y, scale, zp));
        o[6] = f2bf(qdq_act(b.z, scale, zp));
        o[7] = f2bf(qdq_act(b.w, scale, zp));
        *(ushort8*)(out + i) = o;
    }
}

// per-(row, 32-block) symmetric 4-bit weight fake-quant; f32 -> bf16.
// 4 lanes per 32-elem block; coalesced (wave reads 2 KB contiguous).
__device__ __forceinline__ void quant_w_body(const float* __restrict__ W, u16* __restrict__ Wq, long nblk) {
    long ngrp = (long)gridDim.x * blockDim.x / 4;
    long g0 = ((long)blockIdx.x * blockDim.x + threadIdx.x) / 4;
    int j = threadIdx.x & 3;
    for (long b = g0; b < nblk; b += ngrp) {
        const float* p = W + b * 32 + j * 8;
        float4 u0 = *(const float4*)(p);
        float4 u1 = *(const float4*)(p + 4);
        float am = fmaxf(fmaxf(fmaxf(fabsf(u0.x), fabsf(u0.y)), fmaxf(fabsf(u0.z), fabsf(u0.w))),
                         fmaxf(fmaxf(fabsf(u1.x), fabsf(u1.y)), fmaxf(fabsf(u1.z), fabsf(u1.w))));
        am = fmaxf(am, __shfl_xor(am, 1));
        am = fmaxf(am, __shfl_xor(am, 2));
        float scale = fmaxf(am / 7.0f, 1e-12f);
        float inv = 1.0f / scale;
        float v[8] = {u0.x, u0.y, u0.z, u0.w, u1.x, u1.y, u1.z, u1.w};
        ushort8 o;
        #pragma unroll
        for (int t = 0; t < 8; ++t) {
            float q = rintf(v[t] * inv);
            q = fminf(fmaxf(q, -8.0f), 7.0f);
            o[t] = f2bf(q * scale);
        }
        *(ushort8*)(Wq + b * 32 + j * 8) = o;
    }
}
__global__ __launch_bounds__(256) void quant_w_up(const float* W, u16* Wq, long nblk)   { quant_w_body(W, Wq, nblk); }
__global__ __launch_bounds__(256) void quant_w_gate(const float* W, u16* Wq, long nblk) { quant_w_body(W, Wq, nblk); }
__global__ __launch_bounds__(256) void quant_w_down(const float* W, u16* Wq, long nblk) { quant_w_body(W, Wq, nblk); }

// elementwise chain: g1=qdq(gate); sig=fixed_qdq(sigmoid(g1)); g2=g1*sig;
// STAGE1: minmax(g2) -> SLOT_G2
// STAGE2: o = qdq(g2)*qdq(up); minmax(o) -> SLOT_O
// STAGE3: out = bf16(qdq(o))   (out aliases gate; same-index RAW per thread)
template <int STAGEI>
__device__ __forceinline__ void epass_body(const u16* gate, const u16* up, u16* out,
                                           long n, unsigned* slots) {
    float g_s, g_z, u_s = 1.f, u_z = 0.f, g2_s = 1.f, g2_z = 0.f, o_s = 1.f, o_z = 0.f;
    get_scale_zp(slots, SLOT_GATE, g_s, g_z);
    if (STAGEI >= 2) {
        get_scale_zp(slots, SLOT_UP, u_s, u_z);
        get_scale_zp(slots, SLOT_G2, g2_s, g2_z);
    }
    if (STAGEI >= 3) get_scale_zp(slots, SLOT_O, o_s, o_z);

    long stride = (long)gridDim.x * blockDim.x * 8;
    float mn = 0.f, mx = 0.f;
    for (long i = ((long)blockIdx.x * blockDim.x + threadIdx.x) * 8; i < n; i += stride) {
        ushort8 gv = *(const ushort8*)(gate + i);
        ushort8 uv;
        if (STAGEI >= 2) uv = *(const ushort8*)(up + i);
        ushort8 ov;
        #pragma unroll
        for (int j = 0; j < 8; ++j) {
            float g1 = qdq_act(bf2f(gv[j]), g_s, g_z);
            float s = 1.0f / (1.0f + __expf(-g1));
            float sq = fminf(fmaxf(rintf(s * 65536.0f), 0.0f), 65535.0f) * (1.0f / 65536.0f);
            float g2 = g1 * sq;
            if (STAGEI == 1) {
                mn = fminf(mn, g2);
                mx = fmaxf(mx, g2);
            } else {
                float g2q = qdq_act(g2, g2_s, g2_z);
                float u1 = qdq_act(bf2f(uv[j]), u_s, u_z);
                float o = g2q * u1;
                if (STAGEI == 2) {
                    mn = fminf(mn, o);
                    mx = fmaxf(mx, o);
                } else {
                    ov[j] = f2bf(qdq_act(o, o_s, o_z));
                }
            }
        }
        if (STAGEI == 3) *(ushort8*)(out + i) = ov;
    }
    if (STAGEI == 1) wave_minmax_atomic(mn, mx, slots, SLOT_G2);
    if (STAGEI == 2) wave_minmax_atomic(mn, mx, slots, SLOT_O);
}
__global__ __launch_bounds__(256) void epass1(const u16* g, const u16* u, u16* o, long n, unsigned* s) { epass_body<1>(g, u, o, n, s); }
__global__ __launch_bounds__(256) void epass2(const u16* g, const u16* u, u16* o, long n, unsigned* s) { epass_body<2>(g, u, o, n, s); }
__global__ __launch_bounds__(256) void epass3(const u16* g, const u16* u, u16* o, long n, unsigned* s) { epass_body<3>(g, u, o, n, s); }

// ---------------------------------------------------------------------------
// C = A @ B^T : A [M,K] bf16 row-major, B [N,K] bf16 row-major.
// C is bf16 (u16) or f32 per OutT. 128x128 tile, BK=64, 4 waves (2x2),
// each wave 64x64 via 4x4 mfma_16x16x32. Optionally fuses global min/max.
// Grid: 1D supertiled (SUPER_M=16, bm-inner) -> working set L3-resident.
// __launch_bounds__(256,4): 4 blocks/CU. DO NOT raise to 5: wave needs
// 60 VGPR + 64 acc = 124 unified regs > 512/5 budget -> acc spills to
// scratch (measured R7: WRITE_SIZE 89 MB -> 2.7 GB, 510 -> 1190 us).
template <bool MINMAX, typename OutT>
__device__ __forceinline__ void gemm_body(const u16* __restrict__ A, const u16* __restrict__ B,
                                          OutT* __restrict__ C, int M, int N, int K,
                                          unsigned* slots, int sidx) {
    __shared__ u16 Als[128 * 64];
    __shared__ u16 Bls[128 * 64];
    const int wave = threadIdx.x >> 6;
    const int lane = threadIdx.x & 63;
    const int wr = wave >> 1, wc = wave & 1;
    const int l15 = lane & 15, lhi = lane >> 4;

    // supertile mapping: stripes of 16 bm; within a stripe bm varies fastest
    const int ntn = N >> 7;
    const int rowspan = 16 * ntn;
    const int stripe = blockIdx.x / rowspan;
    const int rem = blockIdx.x - stripe * rowspan;
    const int bn = rem >> 4;
    const int bm = (stripe << 4) + (rem & 15);

    f32x4 acc[4][4] = {};

    const u16* Abase = A + (size_t)bm * 128 * K;
    const u16* Bbase = B + (size_t)bn * 128 * K;

    for (int k0 = 0; k0 < K; k0 += 64) {
        #pragma unroll
        for (int i = 0; i < 4; ++i) {
            int c = i * 4 + wave;            // 16 chunks of 512 elems (1KB/wave-inst)
            int e = c * 512 + lane * 8;
            int row = e >> 6, col = e & 63;
            load_lds16(Abase + (size_t)row * K + k0 + col, &Als[c * 512]);
        }
        #pragma unroll
        for (int i = 0; i < 4; ++i) {
            int c = i * 4 + wave;
            int e = c * 512 + lane * 8;
            int row = e >> 6, col = e & 63;
            load_lds16(Bbase + (size_t)row * K + k0 + col, &Bls[c * 512]);
        }
        __syncthreads();
        #pragma unroll
        for (int kk = 0; kk < 64; kk += 32) {
            bf16x8 af[4], bfr[4];
            #pragma unroll
            for (int m = 0; m < 4; ++m)
                af[m] = *(const bf16x8*)&Als[(wr * 64 + m * 16 + l15) * 64 + kk + lhi * 8];
            #pragma unroll
            for (int n = 0; n < 4; ++n)
                bfr[n] = *(const bf16x8*)&Bls[(wc * 64 + n * 16 + l15) * 64 + kk + lhi * 8];
            #pragma unroll
            for (int m = 0; m < 4; ++m)
                #pragma unroll
                for (int n = 0; n < 4; ++n)
                    acc[m][n] = __builtin_amdgcn_mfma_f32_16x16x32_bf16(af[m], bfr[n], acc[m][n], 0, 0, 0);
        }
        __syncthreads();
    }

    float mn = 0.f, mx = 0.f;
    #pragma unroll
    for (int m = 0; m < 4; ++m) {
        #pragma unroll
        for (int n = 0; n < 4; ++n) {
            int col = bn * 128 + wc * 64 + n * 16 + l15;
            int row0 = bm * 128 + wr * 64 + m * 16 + lhi * 4;
            #pragma unroll
            for (int j = 0; j < 4; ++j) {
                float f = acc[m][n][j];
                if (sizeof(OutT) == 2) {
                    u16 h = f2bf(f);
                    ((u16*)C)[(size_t)(row0 + j) * N + col] = h;
                    if (MINMAX) {
                        float g = bf2f(h);
                        mn = fminf(mn, g);
                        mx = fmaxf(mx, g);
                    }
                } else {
                    ((float*)C)[(size_t)(row0 + j) * N + col] = f;
                    if (MINMAX) {
                        mn = fminf(mn, f);
                        mx = fmaxf(mx, f);
                    }
                }
            }
        }
    }
    if (MINMAX) wave_minmax_atomic(mn, mx, slots, sidx);
}

__global__ __launch_bounds__(256, 4) void gemm_up(const u16* A, const u16* B, u16* C,
                                                  int M, int N, int K, unsigned* slots, int sidx) {
    gemm_body<true, u16>(A, B, C, M, N, K, slots, sidx);
}
__global__ __launch_bounds__(256, 4) void gemm_gate(const u16* A, const u16* B, u16* C,
                                                    int M, int N, int K, unsigned* slots, int sidx) {
    gemm_body<true, u16>(A, B, C, M, N, K, slots, sidx);
}
__global__ __launch_bounds__(256, 4) void gemm_down(const u16* A, const u16* B, float* C,
                                                    int M, int N, int K, unsigned* slots, int sidx) {
    gemm_body<false, float>(A, B, C, M, N, K, slots, sidx);
}

// ---------------------------------------------------------------------------
extern "C" void kernel_launch(void* const* d_in, const int* in_sizes, int n_in,
                              void* d_out, int out_size, void* d_ws, size_t ws_size,
                              hipStream_t stream) {
    const float* x  = (const float*)d_in[0];   // [2,2048,4096] f32
    const float* wg = (const float*)d_in[1];   // [11008,4096] f32
    const float* wu = (const float*)d_in[2];   // [11008,4096] f32
    const float* wd = (const float*)d_in[3];   // [4096,11008] f32
    float* out = (float*)d_out;                // [2,2048,4096] f32

    const int M = 4096, H = 4096, I = 11008;
    const long NX = (long)M * H;
    const long NW = (long)I * H;

    char* ws = (char*)d_ws;
    unsigned* slots = (unsigned*)ws;
    u16* xq    = (u16*)(ws + 256);
    u16* wqs   = (u16*)(ws + 256 + 33554432UL);
    u16* upb   = (u16*)(ws + 256 + 33554432UL + 90177536UL);
    u16* gateb = (u16*)(ws + 256 + 33554432UL + 2 * 90177536UL);

    init_slots<<<1, 64, 0, stream>>>(slots);
    minmax_x<<<2048, 256, 0, stream>>>(x, NX, slots, SLOT_X);
    qdq_x_kernel<<<2048, 256, 0, stream>>>(x, xq, NX, slots, SLOT_X);

    const int nwg_ug = (M / 128) * (I / 128);   // 32*86 = 2752
    const int nwg_d  = (M / 128) * (H / 128);   // 32*32 = 1024

    quant_w_up<<<2048, 256, 0, stream>>>(wu, wqs, NW / 32);
    gemm_up<<<nwg_ug, 256, 0, stream>>>(xq, wqs, upb, M, I, H, slots, SLOT_UP);

    quant_w_gate<<<2048, 256, 0, stream>>>(wg, wqs, NW / 32);
    gemm_gate<<<nwg_ug, 256, 0, stream>>>(xq, wqs, gateb, M, I, H, slots, SLOT_GATE);

    epass1<<<4096, 256, 0, stream>>>(gateb, nullptr, nullptr, NW, slots);
    epass2<<<4096, 256, 0, stream>>>(gateb, upb, nullptr, NW, slots);
    epass3<<<4096, 256, 0, stream>>>(gateb, upb, gateb, NW, slots);

    quant_w_down<<<2048, 256, 0, stream>>>(wd, wqs, NW / 32);
    gemm_down<<<nwg_d, 256, 0, stream>>>(gateb, wqs, out, M, H, I, nullptr, 0);
}